// Round 9
// baseline (488.635 us; speedup 1.0000x reference)
//
#include <hip/hip_runtime.h>
#include <hip/hip_bf16.h>
#include <math.h>

#define N_NODES 50000
#define N_EDGES 800000
#define N_GRAPHS 64
#define IN_DIM 128
#define HID 64
#define HEADS 4
#define LAT 32
#define SCAN_BLOCKS ((N_NODES + 255) / 256)   // 196
#define ES_CAP 960000                          // 800k + <=3 pad per node + slack

typedef __attribute__((ext_vector_type(8))) short bf16x8;
typedef __attribute__((ext_vector_type(4))) float floatx4;
typedef __attribute__((ext_vector_type(2))) float f32x2;

__device__ inline unsigned short f2bf(float f) {   // RNE
    unsigned u = __float_as_uint(f);
    return (unsigned short)((u + 0x7fffu + ((u >> 16) & 1u)) >> 16);
}

__device__ inline f32x2 bfpair(unsigned u) {   // packed bf16x2 -> f32x2
    f32x2 r;
    r.x = __uint_as_float(u << 16);
    r.y = __uint_as_float(u & 0xffff0000u);
    return r;
}

// full sum over each 16-lane DPP row via 4 rotational adds (VALU, no DS).
__device__ inline float rowsum16(float x) {
    x += __int_as_float(__builtin_amdgcn_mov_dpp(__float_as_int(x), 0x128, 0xf, 0xf, false));
    x += __int_as_float(__builtin_amdgcn_mov_dpp(__float_as_int(x), 0x124, 0xf, 0xf, false));
    x += __int_as_float(__builtin_amdgcn_mov_dpp(__float_as_int(x), 0x122, 0xf, 0xf, false));
    x += __int_as_float(__builtin_amdgcn_mov_dpp(__float_as_int(x), 0x121, 0xf, 0xf, false));
    return x;
}

// ---------------------------------------------------------------------------
// Counting-sort of edges by dst (per-node slots rounded up to x4: 16B-aligned
// segments for int4 broadcast loads). cnt = true degree; sc = scatter cursor.
// ---------------------------------------------------------------------------
__global__ __launch_bounds__(256) void deg_kernel(const int* __restrict__ dsts,
                                                  int* __restrict__ cnt, int E) {
    int e = blockIdx.x * 256 + threadIdx.x;
    if (e < E) atomicAdd(&cnt[dsts[e]], 1);
}

__global__ __launch_bounds__(256) void sum_kernel(const int* __restrict__ cnt,
                                                  int* __restrict__ bsum) {
    __shared__ int s[256];
    int i = blockIdx.x * 256 + threadIdx.x;
    int c = (i < N_NODES) ? cnt[i] : 0;
    s[threadIdx.x] = (c + 3) & ~3;
    __syncthreads();
    for (int off = 128; off; off >>= 1) {
        if (threadIdx.x < off) s[threadIdx.x] += s[threadIdx.x + off];
        __syncthreads();
    }
    if (threadIdx.x == 0) bsum[blockIdx.x] = s[0];
}

__global__ __launch_bounds__(256) void scan_blocks_kernel(const int* __restrict__ bsum,
                                                          int* __restrict__ boffs) {
    __shared__ int buf[256];
    int t = threadIdx.x;
    int v = (t < SCAN_BLOCKS) ? bsum[t] : 0;
    buf[t] = v;
    __syncthreads();
    #pragma unroll
    for (int off = 1; off < 256; off <<= 1) {
        int tmp = (t >= off) ? buf[t - off] : 0;
        __syncthreads();
        buf[t] += tmp;
        __syncthreads();
    }
    if (t < SCAN_BLOCKS) boffs[t] = buf[t] - v;
}

__global__ __launch_bounds__(256) void scan_final_kernel(const int* __restrict__ cnt,
                                                         const int* __restrict__ boffs,
                                                         int* __restrict__ offs,
                                                         int* __restrict__ sc) {
    __shared__ int buf[256];
    int t = threadIdx.x;
    int i = blockIdx.x * 256 + t;
    int v = 0;
    if (i < N_NODES) v = (cnt[i] + 3) & ~3;
    buf[t] = v;
    __syncthreads();
    #pragma unroll
    for (int off = 1; off < 256; off <<= 1) {
        int tmp = (t >= off) ? buf[t - off] : 0;
        __syncthreads();
        buf[t] += tmp;
        __syncthreads();
    }
    if (i < N_NODES) {
        offs[i] = boffs[blockIdx.x] + buf[t] - v;   // exclusive, 16B-aligned
        sc[i] = 0;
    }
}

__global__ __launch_bounds__(256) void scatter_kernel(const int* __restrict__ srcs,
                                                      const int* __restrict__ dsts,
                                                      const int* __restrict__ offs,
                                                      int* __restrict__ sc,
                                                      int* __restrict__ es, int E) {
    int e = blockIdx.x * 256 + threadIdx.x;
    if (e < E) {
        int d = dsts[e];
        int pos = offs[d] + atomicAdd(&sc[d], 1);
        es[pos] = srcs[e];
    }
}

// ---------------------------------------------------------------------------
// x (fp32) -> bf16 packed
// ---------------------------------------------------------------------------
__global__ __launch_bounds__(256) void conv_kernel(const float* __restrict__ x,
                                                   unsigned* __restrict__ xbf) {
    int i = blockIdx.x * 256 + threadIdx.x;   // one per 2 elements
    if (i < N_NODES * IN_DIM / 2) {
        float2 v = reinterpret_cast<const float2*>(x)[i];
        xbf[i] = (unsigned)f2bf(v.x) | ((unsigned)f2bf(v.y) << 16);
    }
}

// ---------------------------------------------------------------------------
// Pack all 3 layers' Wl|Wr (fp32 [K,256]) into MFMA B-fragment order, bf16.
// tiles 0..15 -> Wl, 16..31 -> Wr.
// COLUMN-INTERLEAVED PAIRING: frag col n of tile pair (2t,2t+1) maps to
// actual cols 32t+2n / 32t+2n+1, so the GEMM epilogue can pack two bf16
// (adjacent cols) into one dword store.
// ---------------------------------------------------------------------------
__global__ __launch_bounds__(256) void pack3_kernel(
    const float* __restrict__ Wl0, const float* __restrict__ Wr0,
    const float* __restrict__ Wl1, const float* __restrict__ Wr1,
    const float* __restrict__ Wl2, const float* __restrict__ Wr2,
    unsigned short* __restrict__ B0, unsigned short* __restrict__ B1,
    unsigned short* __restrict__ B2) {
    int idx = blockIdx.x * 256 + threadIdx.x;   // 0 .. 131071
    const float *Wl, *Wr;
    unsigned short* B;
    int KC, local;
    if (idx < 65536)       { Wl = Wl0; Wr = Wr0; B = B0; KC = 4; local = idx; }
    else if (idx < 98304)  { Wl = Wl1; Wr = Wr1; B = B1; KC = 2; local = idx - 65536; }
    else                   { Wl = Wl2; Wr = Wr2; B = B2; KC = 2; local = idx - 98304; }
    int j = local & 7;
    int lane = (local >> 3) & 63;
    int rem = local >> 9;
    int kc = rem % KC;
    int tile = rem / KC;
    int k = kc * 32 + (lane >> 4) * 8 + j;
    int tt = tile & 15;
    int n = (tt >> 1) * 32 + 2 * (lane & 15) + (tt & 1);   // interleaved pairing
    const float* W = (tile < 16) ? Wl : Wr;
    B[local] = f2bf(W[k * 256 + n]);
}

// ---------------------------------------------------------------------------
// MFMA GEMM: [xl|xr][n,256] (both bf16) = Abf[n,K](bf16) @ [Wl|Wr] (packed).
// Block = 16 rows x 512 cols, 4 waves x 4 tile-PAIRS. Epilogue packs the
// pair's adjacent columns into dword stores (16 stores/lane, was 128 shorts).
// ---------------------------------------------------------------------------
template <int K>
__global__ __launch_bounds__(256) void gemm_mfma_kernel(
    const unsigned short* __restrict__ Abf,
    const unsigned short* __restrict__ Bpk,
    unsigned* __restrict__ xlp_u,
    unsigned* __restrict__ xrp_u) {
    constexpr int KC = K / 32;
    constexpr int CHUNKS = 16 * K / 8;        // 256 (K=128) or 128 (K=64)
    __shared__ short As[CHUNKS * 8];
    int br = blockIdx.x * 16;                 // 50000 = 16*3125 exactly
    int t = threadIdx.x;
    if (t < CHUNKS) {
        int row = t & 15;
        int kcol = (t >> 6) * 32 + ((t >> 4) & 3) * 8;
        *reinterpret_cast<uint4*>(&As[t * 8]) =
            *reinterpret_cast<const uint4*>(&Abf[(size_t)(br + row) * K + kcol]);
    }
    __syncthreads();
    int wave = t >> 6, lane = t & 63;
    int quad = lane >> 4, l16 = lane & 15;
    bf16x8 afrag[KC];
    #pragma unroll
    for (int kc = 0; kc < KC; ++kc)
        afrag[kc] = *reinterpret_cast<const bf16x8*>(&As[((kc * 4 + quad) * 16 + l16) * 8]);
    #pragma unroll
    for (int pr = 0; pr < 4; ++pr) {
        int T = wave * 8 + pr * 2;            // even tile of the pair
        floatx4 acc0 = {0.f, 0.f, 0.f, 0.f};
        floatx4 acc1 = {0.f, 0.f, 0.f, 0.f};
        #pragma unroll
        for (int kc = 0; kc < KC; ++kc) {
            bf16x8 b0 = *reinterpret_cast<const bf16x8*>(
                &Bpk[(size_t)((T * KC + kc) * 64 + lane) * 8]);
            bf16x8 b1 = *reinterpret_cast<const bf16x8*>(
                &Bpk[(size_t)(((T + 1) * KC + kc) * 64 + lane) * 8]);
            acc0 = __builtin_amdgcn_mfma_f32_16x16x32_bf16(afrag[kc], b0, acc0, 0, 0, 0);
            acc1 = __builtin_amdgcn_mfma_f32_16x16x32_bf16(afrag[kc], b1, acc1, 0, 0, 0);
        }
        int tt = T & 15;
        unsigned* dst = (T < 16) ? xlp_u : xrp_u;
        int ci = (tt >> 1) * 16 + l16;        // dword col index (2 cols/dword)
        #pragma unroll
        for (int r = 0; r < 4; ++r) {
            unsigned pk = (unsigned)f2bf(acc0[r]) | ((unsigned)f2bf(acc1[r]) << 16);
            dst[(size_t)(br + quad * 4 + r) * 128 + ci] = pk;
        }
    }
}

// ---------------------------------------------------------------------------
// Attention: ONE 64-lane wave per node (4 nodes / 256-block).
// lane = h*16 + dq (head h, dims 4*dq..4*dq+3), 4 edges in flight.
//  - edge indices: wave-uniform int4 broadcast load (aligned segments)
//  - logit reduce: 4 DPP rotational adds (no DS in edge loop)
//  - att pre-scaled by log2(e) -> exp2f (bare v_exp_f32)
//  - ungated full-quad loop + one gated tail quad
// ---------------------------------------------------------------------------
__global__ __launch_bounds__(256) void attn_kernel(const unsigned* __restrict__ xlp,
                                                   const unsigned* __restrict__ xrp,
                                                   const int* __restrict__ es,
                                                   const int* __restrict__ offs,
                                                   const int* __restrict__ deg,
                                                   const float4* __restrict__ att4,
                                                   const float4* __restrict__ bias4,
                                                   float* __restrict__ hout,
                                                   unsigned* __restrict__ hbf) {
    int node = blockIdx.x * 4 + (threadIdx.x >> 6);
    int lane = threadIdx.x & 63;
    int dn = deg[node];
    int beg = offs[node];
    uint2 xr2 = reinterpret_cast<const uint2*>(xrp)[(size_t)node * 64 + lane];
    f32x2 xrA = bfpair(xr2.x), xrB = bfpair(xr2.y);
    float4 at_t = att4[lane];
    const float L2E = 1.4426950408889634f;
    f32x2 atA = {at_t.x * L2E, at_t.y * L2E};
    f32x2 atB = {at_t.z * L2E, at_t.w * L2E};
    const char* xbase = (const char*)xlp;
    int laneoff = lane << 3;

    float l = 0.f;
    f32x2 accA = {0.f, 0.f}, accB = {0.f, 0.f};

    auto edge_z = [&](uint2 v, f32x2& xa, f32x2& xb) -> float {
        xa = bfpair(v.x);
        xb = bfpair(v.y);
        f32x2 ea = xa + xrA;
        f32x2 eb = xb + xrB;
        ea = __builtin_elementwise_max(ea, ea * 0.2f);
        eb = __builtin_elementwise_max(eb, eb * 0.2f);
        f32x2 zz = ea * atA;
        zz += eb * atB;
        return zz.x + zz.y;
    };
    auto gather = [&](int s) -> uint2 {
        return *reinterpret_cast<const uint2*>(
            xbase + (((size_t)(unsigned)s) << 9) + laneoff);
    };

    int nfull = dn >> 2;
    int cb = beg;
    for (int q = 0; q < nfull; ++q, cb += 4) {
        int4 s4 = *reinterpret_cast<const int4*>(&es[cb]);   // uniform broadcast
        uint2 v0 = gather(s4.x);
        uint2 v1 = gather(s4.y);
        uint2 v2 = gather(s4.z);
        uint2 v3 = gather(s4.w);
        f32x2 xa0, xb0, xa1, xb1, xa2, xb2, xa3, xb3;
        float z0 = rowsum16(edge_z(v0, xa0, xb0));
        float z1 = rowsum16(edge_z(v1, xa1, xb1));
        float z2 = rowsum16(edge_z(v2, xa2, xb2));
        float z3 = rowsum16(edge_z(v3, xa3, xb3));
        float p0 = exp2f(z0);
        float p1 = exp2f(z1);
        float p2 = exp2f(z2);
        float p3 = exp2f(z3);
        accA += p0 * xa0 + p1 * xa1 + p2 * xa2 + p3 * xa3;
        accB += p0 * xb0 + p1 * xb1 + p2 * xb2 + p3 * xb3;
        l += (p0 + p1) + (p2 + p3);
    }
    int rem = dn & 3;
    if (rem) {   // tail quad: edges cb..cb+rem-1 valid; pad slots gated off
        int4 s4 = *reinterpret_cast<const int4*>(&es[cb]);
        uint2 v0 = gather(s4.x);
        uint2 v1 = gather(s4.y);
        uint2 v2 = gather(s4.z);
        f32x2 xa0, xb0, xa1, xb1, xa2, xb2;
        float z0 = rowsum16(edge_z(v0, xa0, xb0));
        float z1 = rowsum16(edge_z(v1, xa1, xb1));
        float z2 = rowsum16(edge_z(v2, xa2, xb2));
        float p0 = exp2f(z0);
        float p1 = (rem > 1) ? exp2f(z1) : 0.f;
        float p2 = (rem > 2) ? exp2f(z2) : 0.f;
        accA += p0 * xa0 + p1 * xa1 + p2 * xa2;
        accB += p0 * xb0 + p1 * xb1 + p2 * xb2;
        l += p0 + p1 + p2;
    }

    float inv = 1.f / (l + 1e-16f);
    float a0 = accA.x * inv, a1 = accA.y * inv;
    float a2 = accB.x * inv, a3 = accB.y * inv;
    // mean over heads: lanes h*16+dq -> sum across h via xor 16, 32
    a0 += __shfl_xor(a0, 16); a0 += __shfl_xor(a0, 32);
    a1 += __shfl_xor(a1, 16); a1 += __shfl_xor(a1, 32);
    a2 += __shfl_xor(a2, 16); a2 += __shfl_xor(a2, 32);
    a3 += __shfl_xor(a3, 16); a3 += __shfl_xor(a3, 32);
    if (lane < 16) {
        float4 bv = bias4[lane];
        float4 o;
        o.x = 0.25f * a0 + bv.x; o.x = (o.x > 0.f) ? o.x : 0.1f * o.x;
        o.y = 0.25f * a1 + bv.y; o.y = (o.y > 0.f) ? o.y : 0.1f * o.y;
        o.z = 0.25f * a2 + bv.z; o.z = (o.z > 0.f) ? o.z : 0.1f * o.z;
        o.w = 0.25f * a3 + bv.w; o.w = (o.w > 0.f) ? o.w : 0.1f * o.w;
        if (hout)
            *reinterpret_cast<float4*>(&hout[(size_t)node * HID + lane * 4]) = o;
        if (hbf) {
            uint2 pk;
            pk.x = (unsigned)f2bf(o.x) | ((unsigned)f2bf(o.y) << 16);
            pk.y = (unsigned)f2bf(o.z) | ((unsigned)f2bf(o.w) << 16);
            *reinterpret_cast<uint2*>(&hbf[(size_t)node * 32 + lane * 2]) = pk;
        }
    }
}

// ---------------------------------------------------------------------------
// Pool: batch sorted -> accumulate runs locally, flush on graph change.
// ---------------------------------------------------------------------------
__global__ __launch_bounds__(256) void pool_kernel(const float* __restrict__ hfin,
                                                   const int* __restrict__ batch,
                                                   float* __restrict__ pooled) {
    int base = blockIdx.x * 256;
    int g = threadIdx.x >> 6, lane = threadIdx.x & 63;
    int lim = min(base + 256, N_NODES);
    int cur = -1;
    float s = 0.f;
    for (int i = base + g; i < lim; i += 4) {
        int b = batch[i];
        if (b != cur) {
            if (cur >= 0) atomicAdd(&pooled[cur * HID + lane], s);
            cur = b; s = 0.f;
        }
        s += hfin[(size_t)i * HID + lane];
    }
    if (cur >= 0) atomicAdd(&pooled[cur * HID + lane], s);
}

// ---------------------------------------------------------------------------
// BN over graphs (biased var) + FC. Single block.
// ---------------------------------------------------------------------------
__global__ __launch_bounds__(256) void final_kernel(const float* __restrict__ pooled,
                                                    const float* __restrict__ gamma,
                                                    const float* __restrict__ beta,
                                                    const float* __restrict__ fcW,
                                                    const float* __restrict__ fcb,
                                                    float* __restrict__ out) {
    __shared__ float P[N_GRAPHS * HID];
    __shared__ float normS[N_GRAPHS * HID];
    __shared__ float meanS[HID], rstdS[HID];
    int t = threadIdx.x;
    for (int i = t; i < N_GRAPHS * HID; i += 256) P[i] = pooled[i];
    __syncthreads();
    if (t < HID) {
        float s = 0.f;
        for (int g = 0; g < N_GRAPHS; ++g) s += P[g * HID + t];
        float mean = s / (float)N_GRAPHS;
        float v = 0.f;
        for (int g = 0; g < N_GRAPHS; ++g) {
            float dd = P[g * HID + t] - mean;
            v += dd * dd;
        }
        v /= (float)N_GRAPHS;
        meanS[t] = mean;
        rstdS[t] = rsqrtf(v + 1e-5f);
    }
    __syncthreads();
    for (int i = t; i < N_GRAPHS * HID; i += 256) {
        int d = i & 63;
        normS[i] = (P[i] - meanS[d]) * rstdS[d] * gamma[d] + beta[d];
    }
    __syncthreads();
    for (int i = t; i < N_GRAPHS * LAT; i += 256) {
        int g = i >> 5, lat = i & 31;
        float s = fcb[lat];
        for (int d = 0; d < HID; ++d) s += normS[g * HID + d] * fcW[lat * HID + d];
        out[i] = s;
    }
}

// ---------------------------------------------------------------------------
extern "C" void kernel_launch(void* const* d_in, const int* in_sizes, int n_in,
                              void* d_out, int out_size, void* d_ws, size_t ws_size,
                              hipStream_t stream) {
    const float* x      = (const float*)d_in[0];
    const int*   ei     = (const int*)d_in[1];
    const int*   batch  = (const int*)d_in[2];
    const float* Wl[3]  = {(const float*)d_in[3], (const float*)d_in[7],  (const float*)d_in[11]};
    const float* Wr[3]  = {(const float*)d_in[4], (const float*)d_in[8],  (const float*)d_in[12]};
    const float* att[3] = {(const float*)d_in[5], (const float*)d_in[9],  (const float*)d_in[13]};
    const float* bia[3] = {(const float*)d_in[6], (const float*)d_in[10], (const float*)d_in[14]};
    const float* gamma  = (const float*)d_in[15];
    const float* beta   = (const float*)d_in[16];
    const float* fcW    = (const float*)d_in[17];
    const float* fcb    = (const float*)d_in[18];
    float* out = (float*)d_out;

    char* p = (char*)d_ws;
    auto alloc = [&](size_t bytes) {
        char* r = p;
        p += (bytes + 255) & ~(size_t)255;
        return r;
    };
    unsigned* xbf   = (unsigned*)alloc((size_t)N_NODES * IN_DIM * 2);   // bf16 x; reused as hfin
    unsigned* xlp   = (unsigned*)alloc((size_t)N_NODES * 256 * 2);
    unsigned* xrp   = (unsigned*)alloc((size_t)N_NODES * 256 * 2);
    unsigned* hbf0  = (unsigned*)alloc((size_t)N_NODES * HID * 2);
    unsigned* hbf1  = (unsigned*)alloc((size_t)N_NODES * HID * 2);
    unsigned short* Bpk0 = (unsigned short*)alloc(32 * 4 * 512 * 2);
    unsigned short* Bpk1 = (unsigned short*)alloc(32 * 2 * 512 * 2);
    unsigned short* Bpk2 = (unsigned short*)alloc(32 * 2 * 512 * 2);
    int*   es      = (int*)alloc((size_t)ES_CAP * 4);
    int*   offs    = (int*)alloc((size_t)N_NODES * 4);
    int*   cnt     = (int*)alloc((size_t)N_NODES * 4);   // true degrees (kept)
    int*   sc      = (int*)alloc((size_t)N_NODES * 4);   // scatter cursors
    int*   bsum    = (int*)alloc((size_t)SCAN_BLOCKS * 4);
    int*   boffs   = (int*)alloc((size_t)SCAN_BLOCKS * 4);
    float* pooled  = (float*)alloc((size_t)N_GRAPHS * HID * 4);
    float* hfin    = (float*)xbf;   // alias: xbf dead after layer-0 GEMM

    const int* srcs = ei;
    const int* dsts = ei + N_EDGES;

    // --- preprocessing: x->bf16, pack weights to fragment order ---
    conv_kernel<<<(N_NODES * IN_DIM / 2 + 255) / 256, 256, 0, stream>>>(x, xbf);
    pack3_kernel<<<512, 256, 0, stream>>>(Wl[0], Wr[0], Wl[1], Wr[1], Wl[2], Wr[2],
                                          Bpk0, Bpk1, Bpk2);

    // --- sort edges by dst (counting sort, x4-aligned segments) ---
    hipMemsetAsync(cnt, 0, (size_t)N_NODES * 4, stream);
    hipMemsetAsync(es, 0, (size_t)ES_CAP * 4, stream);   // pad slots -> node 0 (gated off)
    int eb = (N_EDGES + 255) / 256;
    deg_kernel<<<eb, 256, 0, stream>>>(dsts, cnt, N_EDGES);
    sum_kernel<<<SCAN_BLOCKS, 256, 0, stream>>>(cnt, bsum);
    scan_blocks_kernel<<<1, 256, 0, stream>>>(bsum, boffs);
    scan_final_kernel<<<SCAN_BLOCKS, 256, 0, stream>>>(cnt, boffs, offs, sc);
    scatter_kernel<<<eb, 256, 0, stream>>>(srcs, dsts, offs, sc, es, N_EDGES);

    // --- 3 GATv2 layers (GEMM on matrix cores, bf16 in / fp32 acc) ---
    int gb = N_NODES / 16;   // 3125
    // layer 0
    gemm_mfma_kernel<IN_DIM><<<gb, 256, 0, stream>>>((const unsigned short*)xbf, Bpk0, xlp, xrp);
    attn_kernel<<<N_NODES / 4, 256, 0, stream>>>(xlp, xrp, es, offs, cnt,
                                                 (const float4*)att[0],
                                                 (const float4*)bia[0], nullptr, hbf0);
    // layer 1
    gemm_mfma_kernel<HID><<<gb, 256, 0, stream>>>((const unsigned short*)hbf0, Bpk1, xlp, xrp);
    attn_kernel<<<N_NODES / 4, 256, 0, stream>>>(xlp, xrp, es, offs, cnt,
                                                 (const float4*)att[1],
                                                 (const float4*)bia[1], nullptr, hbf1);
    // layer 2
    gemm_mfma_kernel<HID><<<gb, 256, 0, stream>>>((const unsigned short*)hbf1, Bpk2, xlp, xrp);
    attn_kernel<<<N_NODES / 4, 256, 0, stream>>>(xlp, xrp, es, offs, cnt,
                                                 (const float4*)att[2],
                                                 (const float4*)bia[2], hfin, nullptr);

    // --- pool + BN + FC ---
    hipMemsetAsync(pooled, 0, (size_t)N_GRAPHS * HID * 4, stream);
    pool_kernel<<<SCAN_BLOCKS, 256, 0, stream>>>(hfin, batch, pooled);
    final_kernel<<<1, 256, 0, stream>>>(pooled, gamma, beta, fcW, fcb, out);
}

// Round 10
// 479.217 us; speedup vs baseline: 1.0197x; 1.0197x over previous
//
#include <hip/hip_runtime.h>
#include <hip/hip_bf16.h>
#include <math.h>

#define N_NODES 50000
#define N_EDGES 800000
#define N_GRAPHS 64
#define IN_DIM 128
#define HID 64
#define HEADS 4
#define LAT 32
#define SCAN_BLOCKS ((N_NODES + 255) / 256)   // 196
#define ES_CAP 960000                          // 800k + <=3 pad per node + slack

typedef __attribute__((ext_vector_type(8))) short bf16x8;
typedef __attribute__((ext_vector_type(4))) float floatx4;
typedef __attribute__((ext_vector_type(2))) float f32x2;

__device__ inline unsigned short f2bf(float f) {   // RNE
    unsigned u = __float_as_uint(f);
    return (unsigned short)((u + 0x7fffu + ((u >> 16) & 1u)) >> 16);
}

__device__ inline f32x2 bfpair(unsigned u) {   // packed bf16x2 -> f32x2
    f32x2 r;
    r.x = __uint_as_float(u << 16);
    r.y = __uint_as_float(u & 0xffff0000u);
    return r;
}

// full sum over each 16-lane DPP row via 4 rotational adds (VALU, no DS).
__device__ inline float rowsum16(float x) {
    x += __int_as_float(__builtin_amdgcn_mov_dpp(__float_as_int(x), 0x128, 0xf, 0xf, false));
    x += __int_as_float(__builtin_amdgcn_mov_dpp(__float_as_int(x), 0x124, 0xf, 0xf, false));
    x += __int_as_float(__builtin_amdgcn_mov_dpp(__float_as_int(x), 0x122, 0xf, 0xf, false));
    x += __int_as_float(__builtin_amdgcn_mov_dpp(__float_as_int(x), 0x121, 0xf, 0xf, false));
    return x;
}

// ---------------------------------------------------------------------------
// PREP (1 dispatch, replaces conv + pack3 + 3 memsets + done-init):
// blocks [0,3072): x fp32 -> bf16 packed (grid-stride over 3.2M dwords)
// blocks [3072,3584): pack all 3 layers' Wl|Wr into MFMA B-frag order
// blocks [3584,3840): zero cnt / pooled / done
// blocks [3840,4096): zero es (pad slots must be 0 -> node-0 gather, gated off)
// ---------------------------------------------------------------------------
__global__ __launch_bounds__(256) void prep_kernel(
    const float* __restrict__ x, unsigned* __restrict__ xbf,
    const float* __restrict__ Wl0, const float* __restrict__ Wr0,
    const float* __restrict__ Wl1, const float* __restrict__ Wr1,
    const float* __restrict__ Wl2, const float* __restrict__ Wr2,
    unsigned short* __restrict__ B0, unsigned short* __restrict__ B1,
    unsigned short* __restrict__ B2,
    int* __restrict__ cnt, float* __restrict__ pooled, int* __restrict__ done,
    uint4* __restrict__ es4) {
    int b = blockIdx.x, t = threadIdx.x;
    if (b < 3072) {
        for (int i = b * 256 + t; i < N_NODES * IN_DIM / 2; i += 3072 * 256) {
            float2 v = reinterpret_cast<const float2*>(x)[i];
            xbf[i] = (unsigned)f2bf(v.x) | ((unsigned)f2bf(v.y) << 16);
        }
    } else if (b < 3584) {
        int idx = (b - 3072) * 256 + t;   // 0 .. 131071
        const float *Wl, *Wr;
        unsigned short* B;
        int KC, local;
        if (idx < 65536)      { Wl = Wl0; Wr = Wr0; B = B0; KC = 4; local = idx; }
        else if (idx < 98304) { Wl = Wl1; Wr = Wr1; B = B1; KC = 2; local = idx - 65536; }
        else                  { Wl = Wl2; Wr = Wr2; B = B2; KC = 2; local = idx - 98304; }
        int j = local & 7;
        int lane = (local >> 3) & 63;
        int rem = local >> 9;
        int kc = rem % KC;
        int tile = rem / KC;
        int k = kc * 32 + (lane >> 4) * 8 + j;
        int tt = tile & 15;
        int n = (tt >> 1) * 32 + 2 * (lane & 15) + (tt & 1);   // interleaved pairing
        const float* W = (tile < 16) ? Wl : Wr;
        B[local] = f2bf(W[k * 256 + n]);
    } else if (b < 3840) {
        int idx = (b - 3584) * 256 + t;   // 0 .. 65535
        if (idx < N_NODES) cnt[idx] = 0;
        if (idx < N_GRAPHS * HID) pooled[idx] = 0.f;
        if (idx == 0) *done = 0;
    } else {
        int idx = (b - 3840) * 256 + t;   // 0 .. 65535
        for (int i = idx; i < ES_CAP / 4; i += 65536)
            es4[i] = uint4{0, 0, 0, 0};
    }
}

// ---------------------------------------------------------------------------
// Degree histogram
// ---------------------------------------------------------------------------
__global__ __launch_bounds__(256) void deg_kernel(const int* __restrict__ dsts,
                                                  int* __restrict__ cnt, int E) {
    int e = blockIdx.x * 256 + threadIdx.x;
    if (e < E) atomicAdd(&cnt[dsts[e]], 1);
}

// ---------------------------------------------------------------------------
// Single-kernel exclusive scan of x4-padded degrees, decoupled lookback.
// agg[b] published as (blocksum | 0x40000000); ws poison 0xAAAAAAAA is
// negative -> spin-safe without pre-zeroing. 196 blocks co-resident.
// Also zeroes the scatter cursors sc[].
// ---------------------------------------------------------------------------
__global__ __launch_bounds__(256) void scan_kernel(const int* __restrict__ cnt,
                                                   int* __restrict__ offs,
                                                   int* __restrict__ sc,
                                                   int* __restrict__ agg) {
    __shared__ int buf[256];
    int b = blockIdx.x, t = threadIdx.x;
    int i = b * 256 + t;
    int v = (i < N_NODES) ? ((cnt[i] + 3) & ~3) : 0;
    buf[t] = v;
    __syncthreads();
    #pragma unroll
    for (int off = 1; off < 256; off <<= 1) {
        int tmp = (t >= off) ? buf[t - off] : 0;
        __syncthreads();
        buf[t] += tmp;
        __syncthreads();
    }
    int incl = buf[t];
    if (t == 255)
        __hip_atomic_store(&agg[b], buf[255] | 0x40000000,
                           __ATOMIC_RELEASE, __HIP_MEMORY_SCOPE_AGENT);
    int contrib = 0;
    if (t < b) {   // b <= 195 < 256: one predecessor per thread
        int vv;
        do {
            vv = __hip_atomic_load(&agg[t], __ATOMIC_ACQUIRE, __HIP_MEMORY_SCOPE_AGENT);
        } while (vv < 0 || !(vv & 0x40000000));
        contrib = vv & 0x3FFFFFFF;
    }
    __syncthreads();
    buf[t] = contrib;
    __syncthreads();
    for (int off = 128; off; off >>= 1) {
        if (t < off) buf[t] += buf[t + off];
        __syncthreads();
    }
    if (i < N_NODES) {
        offs[i] = buf[0] + incl - v;   // exclusive, 16B-aligned
        sc[i] = 0;
    }
}

__global__ __launch_bounds__(256) void scatter_kernel(const int* __restrict__ srcs,
                                                      const int* __restrict__ dsts,
                                                      const int* __restrict__ offs,
                                                      int* __restrict__ sc,
                                                      int* __restrict__ es, int E) {
    int e = blockIdx.x * 256 + threadIdx.x;
    if (e < E) {
        int d = dsts[e];
        int pos = offs[d] + atomicAdd(&sc[d], 1);
        es[pos] = srcs[e];
    }
}

// ---------------------------------------------------------------------------
// MFMA GEMM: [xl|xr][n,256] (both bf16) = Abf[n,K](bf16) @ [Wl|Wr] (packed).
// Block = 16 rows x 512 cols, 4 waves x 4 tile-pairs; paired-column packed
// dword stores.
// ---------------------------------------------------------------------------
template <int K>
__global__ __launch_bounds__(256) void gemm_mfma_kernel(
    const unsigned short* __restrict__ Abf,
    const unsigned short* __restrict__ Bpk,
    unsigned* __restrict__ xlp_u,
    unsigned* __restrict__ xrp_u) {
    constexpr int KC = K / 32;
    constexpr int CHUNKS = 16 * K / 8;        // 256 (K=128) or 128 (K=64)
    __shared__ short As[CHUNKS * 8];
    int br = blockIdx.x * 16;                 // 50000 = 16*3125 exactly
    int t = threadIdx.x;
    if (t < CHUNKS) {
        int row = t & 15;
        int kcol = (t >> 6) * 32 + ((t >> 4) & 3) * 8;
        *reinterpret_cast<uint4*>(&As[t * 8]) =
            *reinterpret_cast<const uint4*>(&Abf[(size_t)(br + row) * K + kcol]);
    }
    __syncthreads();
    int wave = t >> 6, lane = t & 63;
    int quad = lane >> 4, l16 = lane & 15;
    bf16x8 afrag[KC];
    #pragma unroll
    for (int kc = 0; kc < KC; ++kc)
        afrag[kc] = *reinterpret_cast<const bf16x8*>(&As[((kc * 4 + quad) * 16 + l16) * 8]);
    #pragma unroll
    for (int pr = 0; pr < 4; ++pr) {
        int T = wave * 8 + pr * 2;            // even tile of the pair
        floatx4 acc0 = {0.f, 0.f, 0.f, 0.f};
        floatx4 acc1 = {0.f, 0.f, 0.f, 0.f};
        #pragma unroll
        for (int kc = 0; kc < KC; ++kc) {
            bf16x8 b0 = *reinterpret_cast<const bf16x8*>(
                &Bpk[(size_t)((T * KC + kc) * 64 + lane) * 8]);
            bf16x8 b1 = *reinterpret_cast<const bf16x8*>(
                &Bpk[(size_t)(((T + 1) * KC + kc) * 64 + lane) * 8]);
            acc0 = __builtin_amdgcn_mfma_f32_16x16x32_bf16(afrag[kc], b0, acc0, 0, 0, 0);
            acc1 = __builtin_amdgcn_mfma_f32_16x16x32_bf16(afrag[kc], b1, acc1, 0, 0, 0);
        }
        int tt = T & 15;
        unsigned* dst = (T < 16) ? xlp_u : xrp_u;
        int ci = (tt >> 1) * 16 + l16;        // dword col index (2 cols/dword)
        #pragma unroll
        for (int r = 0; r < 4; ++r) {
            unsigned pk = (unsigned)f2bf(acc0[r]) | ((unsigned)f2bf(acc1[r]) << 16);
            dst[(size_t)(br + quad * 4 + r) * 128 + ci] = pk;
        }
    }
}

// ---------------------------------------------------------------------------
// Attention (R8 body — best measured): ONE 64-lane wave per node.
// lane = h*16 + dq; int4 uniform broadcast of 4 edge indices; DPP rowsum;
// no-max softmax; zero DS in edge loop.
// ---------------------------------------------------------------------------
__global__ __launch_bounds__(256) void attn_kernel(const unsigned* __restrict__ xlp,
                                                   const unsigned* __restrict__ xrp,
                                                   const int* __restrict__ es,
                                                   const int* __restrict__ offs,
                                                   const int* __restrict__ deg,
                                                   const float4* __restrict__ att4,
                                                   const float4* __restrict__ bias4,
                                                   float* __restrict__ hout,
                                                   unsigned* __restrict__ hbf) {
    int node = blockIdx.x * 4 + (threadIdx.x >> 6);
    int lane = threadIdx.x & 63;
    int beg = offs[node];
    int end = beg + deg[node];
    uint2 xr2 = reinterpret_cast<const uint2*>(xrp)[(size_t)node * 64 + lane];
    f32x2 xrA = bfpair(xr2.x), xrB = bfpair(xr2.y);
    float4 at_t = att4[lane];
    f32x2 atA = {at_t.x, at_t.y}, atB = {at_t.z, at_t.w};
    const char* xbase = (const char*)xlp;
    int laneoff = lane << 3;

    float l = 0.f;
    f32x2 accA = {0.f, 0.f}, accB = {0.f, 0.f};

    auto edge_z = [&](uint2 v, f32x2& xa, f32x2& xb) -> float {
        xa = bfpair(v.x);
        xb = bfpair(v.y);
        f32x2 ea = xa + xrA;
        f32x2 eb = xb + xrB;
        ea = __builtin_elementwise_max(ea, ea * 0.2f);
        eb = __builtin_elementwise_max(eb, eb * 0.2f);
        f32x2 zz = ea * atA;
        zz += eb * atB;
        return zz.x + zz.y;
    };
    auto gather = [&](int s) -> uint2 {
        return *reinterpret_cast<const uint2*>(
            xbase + (((size_t)(unsigned)s) << 9) + laneoff);
    };

    for (int cb = beg; cb < end; cb += 4) {
        int4 s4 = *reinterpret_cast<const int4*>(&es[cb]);   // uniform broadcast
        uint2 v0 = gather(s4.x);
        uint2 v1 = gather(s4.y);
        uint2 v2 = gather(s4.z);
        uint2 v3 = gather(s4.w);
        f32x2 xa0, xb0, xa1, xb1, xa2, xb2, xa3, xb3;
        float z0 = rowsum16(edge_z(v0, xa0, xb0));
        float z1 = rowsum16(edge_z(v1, xa1, xb1));
        float z2 = rowsum16(edge_z(v2, xa2, xb2));
        float z3 = rowsum16(edge_z(v3, xa3, xb3));
        float p0 = __expf(z0);                               // cb+0 < end always
        float p1 = (cb + 1 < end) ? __expf(z1) : 0.f;
        float p2 = (cb + 2 < end) ? __expf(z2) : 0.f;
        float p3 = (cb + 3 < end) ? __expf(z3) : 0.f;
        accA += p0 * xa0 + p1 * xa1 + p2 * xa2 + p3 * xa3;
        accB += p0 * xb0 + p1 * xb1 + p2 * xb2 + p3 * xb3;
        l += (p0 + p1) + (p2 + p3);
    }

    float inv = 1.f / (l + 1e-16f);
    float a0 = accA.x * inv, a1 = accA.y * inv;
    float a2 = accB.x * inv, a3 = accB.y * inv;
    a0 += __shfl_xor(a0, 16); a0 += __shfl_xor(a0, 32);
    a1 += __shfl_xor(a1, 16); a1 += __shfl_xor(a1, 32);
    a2 += __shfl_xor(a2, 16); a2 += __shfl_xor(a2, 32);
    a3 += __shfl_xor(a3, 16); a3 += __shfl_xor(a3, 32);
    if (lane < 16) {
        float4 bv = bias4[lane];
        float4 o;
        o.x = 0.25f * a0 + bv.x; o.x = (o.x > 0.f) ? o.x : 0.1f * o.x;
        o.y = 0.25f * a1 + bv.y; o.y = (o.y > 0.f) ? o.y : 0.1f * o.y;
        o.z = 0.25f * a2 + bv.z; o.z = (o.z > 0.f) ? o.z : 0.1f * o.z;
        o.w = 0.25f * a3 + bv.w; o.w = (o.w > 0.f) ? o.w : 0.1f * o.w;
        if (hout)
            *reinterpret_cast<float4*>(&hout[(size_t)node * HID + lane * 4]) = o;
        if (hbf) {
            uint2 pk;
            pk.x = (unsigned)f2bf(o.x) | ((unsigned)f2bf(o.y) << 16);
            pk.y = (unsigned)f2bf(o.z) | ((unsigned)f2bf(o.w) << 16);
            *reinterpret_cast<uint2*>(&hbf[(size_t)node * 32 + lane * 2]) = pk;
        }
    }
}

// ---------------------------------------------------------------------------
// Pool + BN + FC fused: 196 blocks pool (sorted-run atomics); last block to
// finish (device atomic counter) performs BN over graphs + FC.
// ---------------------------------------------------------------------------
__global__ __launch_bounds__(256) void pool_final_kernel(
    const float* __restrict__ hfin, const int* __restrict__ batch,
    float* __restrict__ pooled,
    const float* __restrict__ gamma, const float* __restrict__ beta,
    const float* __restrict__ fcW, const float* __restrict__ fcb,
    float* __restrict__ out, int* __restrict__ done) {
    int base = blockIdx.x * 256;
    int g = threadIdx.x >> 6, lane = threadIdx.x & 63;
    int lim = min(base + 256, N_NODES);
    int cur = -1;
    float s = 0.f;
    for (int i = base + g; i < lim; i += 4) {
        int b = batch[i];
        if (b != cur) {
            if (cur >= 0) atomicAdd(&pooled[cur * HID + lane], s);
            cur = b; s = 0.f;
        }
        s += hfin[(size_t)i * HID + lane];
    }
    if (cur >= 0) atomicAdd(&pooled[cur * HID + lane], s);

    __threadfence();
    __syncthreads();
    __shared__ int lastS;
    if (threadIdx.x == 0)
        lastS = (atomicAdd(done, 1) == (int)gridDim.x - 1);
    __syncthreads();
    if (!lastS) return;

    // ---- final phase (single block) ----
    __shared__ float P[N_GRAPHS * HID];
    __shared__ float normS[N_GRAPHS * HID];
    __shared__ float meanS[HID], rstdS[HID];
    int t = threadIdx.x;
    for (int i = t; i < N_GRAPHS * HID; i += 256)
        P[i] = __hip_atomic_load(&pooled[i], __ATOMIC_RELAXED, __HIP_MEMORY_SCOPE_AGENT);
    __syncthreads();
    if (t < HID) {
        float s2 = 0.f;
        for (int g2 = 0; g2 < N_GRAPHS; ++g2) s2 += P[g2 * HID + t];
        float mean = s2 / (float)N_GRAPHS;
        float v = 0.f;
        for (int g2 = 0; g2 < N_GRAPHS; ++g2) {
            float dd = P[g2 * HID + t] - mean;
            v += dd * dd;
        }
        v /= (float)N_GRAPHS;
        meanS[t] = mean;
        rstdS[t] = rsqrtf(v + 1e-5f);
    }
    __syncthreads();
    for (int i = t; i < N_GRAPHS * HID; i += 256) {
        int d = i & 63;
        normS[i] = (P[i] - meanS[d]) * rstdS[d] * gamma[d] + beta[d];
    }
    __syncthreads();
    for (int i = t; i < N_GRAPHS * LAT; i += 256) {
        int g2 = i >> 5, lat = i & 31;
        float s2 = fcb[lat];
        for (int d = 0; d < HID; ++d) s2 += normS[g2 * HID + d] * fcW[lat * HID + d];
        out[i] = s2;
    }
}

// ---------------------------------------------------------------------------
extern "C" void kernel_launch(void* const* d_in, const int* in_sizes, int n_in,
                              void* d_out, int out_size, void* d_ws, size_t ws_size,
                              hipStream_t stream) {
    const float* x      = (const float*)d_in[0];
    const int*   ei     = (const int*)d_in[1];
    const int*   batch  = (const int*)d_in[2];
    const float* Wl[3]  = {(const float*)d_in[3], (const float*)d_in[7],  (const float*)d_in[11]};
    const float* Wr[3]  = {(const float*)d_in[4], (const float*)d_in[8],  (const float*)d_in[12]};
    const float* att[3] = {(const float*)d_in[5], (const float*)d_in[9],  (const float*)d_in[13]};
    const float* bia[3] = {(const float*)d_in[6], (const float*)d_in[10], (const float*)d_in[14]};
    const float* gamma  = (const float*)d_in[15];
    const float* beta   = (const float*)d_in[16];
    const float* fcW    = (const float*)d_in[17];
    const float* fcb    = (const float*)d_in[18];
    float* out = (float*)d_out;

    char* p = (char*)d_ws;
    auto alloc = [&](size_t bytes) {
        char* r = p;
        p += (bytes + 255) & ~(size_t)255;
        return r;
    };
    unsigned* xbf   = (unsigned*)alloc((size_t)N_NODES * IN_DIM * 2);   // bf16 x; reused as hfin
    unsigned* xlp   = (unsigned*)alloc((size_t)N_NODES * 256 * 2);
    unsigned* xrp   = (unsigned*)alloc((size_t)N_NODES * 256 * 2);
    unsigned* hbf0  = (unsigned*)alloc((size_t)N_NODES * HID * 2);
    unsigned* hbf1  = (unsigned*)alloc((size_t)N_NODES * HID * 2);
    unsigned short* Bpk0 = (unsigned short*)alloc(32 * 4 * 512 * 2);
    unsigned short* Bpk1 = (unsigned short*)alloc(32 * 2 * 512 * 2);
    unsigned short* Bpk2 = (unsigned short*)alloc(32 * 2 * 512 * 2);
    int*   es      = (int*)alloc((size_t)ES_CAP * 4);
    int*   offs    = (int*)alloc((size_t)N_NODES * 4);
    int*   cnt     = (int*)alloc((size_t)N_NODES * 4);   // true degrees
    int*   sc      = (int*)alloc((size_t)N_NODES * 4);   // scatter cursors
    int*   agg     = (int*)alloc((size_t)SCAN_BLOCKS * 4);
    int*   done    = (int*)alloc(256);
    float* pooled  = (float*)alloc((size_t)N_GRAPHS * HID * 4);
    float* hfin    = (float*)xbf;   // alias: xbf dead after layer-0 GEMM

    const int* srcs = ei;
    const int* dsts = ei + N_EDGES;

    // 1: prep (conv + pack + zeros)
    prep_kernel<<<4096, 256, 0, stream>>>(x, xbf, Wl[0], Wr[0], Wl[1], Wr[1],
                                          Wl[2], Wr[2], Bpk0, Bpk1, Bpk2,
                                          cnt, pooled, done, (uint4*)es);
    // 2-4: counting sort (deg -> lookback scan -> scatter)
    int eb = (N_EDGES + 255) / 256;
    deg_kernel<<<eb, 256, 0, stream>>>(dsts, cnt, N_EDGES);
    scan_kernel<<<SCAN_BLOCKS, 256, 0, stream>>>(cnt, offs, sc, agg);
    scatter_kernel<<<eb, 256, 0, stream>>>(srcs, dsts, offs, sc, es, N_EDGES);

    // 5-10: 3 GATv2 layers
    int gb = N_NODES / 16;   // 3125
    gemm_mfma_kernel<IN_DIM><<<gb, 256, 0, stream>>>((const unsigned short*)xbf, Bpk0, xlp, xrp);
    attn_kernel<<<N_NODES / 4, 256, 0, stream>>>(xlp, xrp, es, offs, cnt,
                                                 (const float4*)att[0],
                                                 (const float4*)bia[0], nullptr, hbf0);
    gemm_mfma_kernel<HID><<<gb, 256, 0, stream>>>((const unsigned short*)hbf0, Bpk1, xlp, xrp);
    attn_kernel<<<N_NODES / 4, 256, 0, stream>>>(xlp, xrp, es, offs, cnt,
                                                 (const float4*)att[1],
                                                 (const float4*)bia[1], nullptr, hbf1);
    gemm_mfma_kernel<HID><<<gb, 256, 0, stream>>>((const unsigned short*)hbf1, Bpk2, xlp, xrp);
    attn_kernel<<<N_NODES / 4, 256, 0, stream>>>(xlp, xrp, es, offs, cnt,
                                                 (const float4*)att[2],
                                                 (const float4*)bia[2], hfin, nullptr);

    // 11: pool + BN + FC (last-block-done)
    pool_final_kernel<<<SCAN_BLOCKS, 256, 0, stream>>>(hfin, batch, pooled,
                                                       gamma, beta, fcW, fcb,
                                                       out, done);
}